// Round 5
// baseline (221.922 us; speedup 1.0000x reference)
//
#include <hip/hip_runtime.h>
#include <hip/hip_bf16.h>
#include <cstdint>

#define QLEN   1024
#define KLEN   2048
#define DMODEL 2048
#define BATCH  4
#define FLEN   (KLEN - QLEN + 1)   // 1025

typedef __bf16 bf16x8 __attribute__((ext_vector_type(8)));
typedef float  f32x4  __attribute__((ext_vector_type(4)));

// Static FT fallback (primary: harness workspace — round-3 measured win).
__device__ __align__(16) __bf16 g_ft[(size_t)QLEN * KLEN];           // 4 MiB

typedef __attribute__((address_space(1))) void gvoid;
typedef __attribute__((address_space(3))) void svoid;

__device__ __forceinline__ void async_load16(const void* g, void* lds) {
  gvoid* gp = (gvoid*)(uintptr_t)g;
  svoid* sp = (svoid*)(uint32_t)(uintptr_t)lds;   // flat LDS addr low 32 bits == LDS offset
  __builtin_amdgcn_global_load_lds(gp, sp, 16, 0, 0);
}

// ---------------- prep: FT generation only ----------------
// Round-5: the y^T intermediate is DELETED (4 rounds of prep tuning all pinned
// at ~53-64 us regardless of structure/MLP/placement -> the kernel itself was
// the cost). add+cast is fused into gemm's B-staging; prep only builds FT.
// FT[l,m] = cos(2*pi*((l*(m-l)) % 1025)/1025) / sqrt(1025*2048) inside band.
__global__ __launch_bounds__(256) void prep_ft_kernel(__bf16* __restrict__ ftp) {
  __bf16* ft = ftp ? ftp : g_ft;
  const int uu = blockIdx.x * 256 + threadIdx.x;   // [0, QLEN*KLEN/8)
  const int l  = uu >> 8;                          // KLEN/8 = 256 chunks per row
  const int m0 = (uu & 255) * 8;
  const int j0 = m0 - l;
  bf16x8 o = {};
  if (j0 + 7 >= 0 && j0 < FLEN) {
    const float w     = 6.283185307179586f / (float)FLEN;
    const float scale = 1.0f / sqrtf((float)FLEN * (float)KLEN);
#pragma unroll
    for (int i = 0; i < 8; ++i) {
      const int j = j0 + i;
      float vv = 0.0f;
      if (j >= 0 && j < FLEN) {
        const int rr = (l * j) % FLEN;             // exact: l*j < 2^20, magic-mul mod
        vv = cosf((float)rr * w) * scale;
      }
      o[i] = (__bf16)vv;
    }
  }
  *(bf16x8*)(ft + (size_t)uu * 8) = o;
}

// ---------------- fused GEMM: out[b][l][d] = sum_m FT[l][m] * bf16(x+p)[m][d] ----
#define BM 128
#define BN 128
#define BK 64

// 7-bit XOR swizzle on the B chunk index (chunk = 8 consecutive m for one d).
// Applied identically on ds_write and ds_read -> bijective, and both the write
// lanes (dd = dg*4+j, dg varies) and read lanes (dd = r, col varies) spread
// evenly across all 8 LDS bank groups (naive write pattern = 4-phase conflict).
__device__ __forceinline__ int swz7(int i) { return i ^ ((i >> 3) & 7); }

__global__ __launch_bounds__(256) void gemm_kernel(float* __restrict__ out,
                                                   const __bf16* __restrict__ ftq,
                                                   const float* __restrict__ x,
                                                   const float* __restrict__ p,
                                                   const int* __restrict__ addp) {
  // grid: (DMODEL/BN, QLEN/BM, BATCH); 4 waves; wave tile 64x64 (4x4 of 16x16x32 MFMA)
  __shared__ __align__(16) __bf16 As[BM * BK];   // [l'][k'] chunk-swizzled, 16 KB
  __shared__ __align__(16) __bf16 Bs[BN * BK];   // chunk-major: chunk(c8,dd) at c8*128+swz7(dd), 16 KB
  const int bn = blockIdx.x, bm = blockIdx.y, b = blockIdx.z;
  const int l0 = bm * BM, d0 = bn * BN;
  const int tid  = threadIdx.x;
  const int lane = tid & 63;
  const int wave = tid >> 6;
  const int wr = wave >> 1, wc = wave & 1;
  const int col = lane & 15, quad = lane >> 4;
  const float addf = (*addp) ? 1.0f : 0.0f;

  f32x4 acc[4][4] = {};

  // B-staging ownership: thread -> (cB = m-chunk 0..7, dg = d-group 0..31).
  // Loads: per instr, lanes 0-31 read 512 B contiguous (row t*64+16w+i), lanes
  // 32-63 the row 8 below — fully coalesced f32x4.
  const int cB = tid >> 5;
  const int dg = tid & 31;
  int wsw[4];                                     // precomputed swizzled write idx16
#pragma unroll
  for (int j = 0; j < 4; ++j) wsw[j] = cB * 128 + swz7(dg * 4 + j);
  int rsw[4];                                     // precomputed swizzled read idx16
#pragma unroll
  for (int tj = 0; tj < 4; ++tj) rsw[tj] = swz7(wc * 64 + tj * 16 + col);

  // band: FT[l,m] nonzero only for l <= m <= l+1024 -> K-tiles [l0/64, (l0+1151)/64]
  const int t0 = l0 >> 6;
  const int t1 = (l0 + BM - 1 + FLEN - 1) >> 6;   // inclusive; 18 tiles
  const __bf16* ftp = ftq ? ftq : g_ft;
  const float* xb0 = x + (size_t)b * KLEN * DMODEL + d0 + dg * 4;
  const float* pb0 = p + (size_t)b * KLEN * DMODEL + d0 + dg * 4;

  for (int t = t0; t <= t1; ++t) {
    const int k0 = t * BK;
    // Stage A (FT): 128 rows x 64 k row-major, XOR swizzle on the GLOBAL side
    // (LDS linear; global_load_lds writes lane i at base + i*16). Unchanged.
#pragma unroll
    for (int s = 0; s < 4; ++s) {
      const int cb  = wave * 256 + s * 64;
      const int lc  = cb + lane;
      const int row = lc >> 3;
      const int gc8 = (lc & 7) ^ (row & 7);
      async_load16(ftp + (size_t)(l0 + row) * KLEN + k0 + gc8 * 8, As + cb * 8);
    }
    // Stage B fused: load fp32 x/p sub-tile to regs, add+cast, ds_write chunks.
    // Values are bitwise-identical to the old precomputed yt (bf16(x + addf*p)).
    {
      const float* xb = xb0 + (size_t)(k0 + cB * 8) * DMODEL;
      const float* pb = pb0 + (size_t)(k0 + cB * 8) * DMODEL;
      f32x4 vx[8], vp[8];
#pragma unroll
      for (int i = 0; i < 8; ++i) vx[i] = *(const f32x4*)(xb + (size_t)i * DMODEL);
#pragma unroll
      for (int i = 0; i < 8; ++i) vp[i] = *(const f32x4*)(pb + (size_t)i * DMODEL);
#pragma unroll
      for (int j = 0; j < 4; ++j) {
        bf16x8 o;
#pragma unroll
        for (int i = 0; i < 8; ++i) o[i] = (__bf16)(vx[i][j] + addf * vp[i][j]);
        *(bf16x8*)(Bs + (size_t)wsw[j] * 8) = o;   // ds_write_b128, conflict-free via swz7
      }
    }
    __syncthreads();   // drains vmcnt (A async) + lgkm (Bs writes) -> tiles visible

#pragma unroll
    for (int kk = 0; kk < 2; ++kk) {
      bf16x8 af[4], bq[4];
      const int c8 = kk * 4 + quad;
#pragma unroll
      for (int ti = 0; ti < 4; ++ti) {
        const int r = wr * 64 + ti * 16 + col;            // A row (l), frag m = lane&15
        af[ti] = *(const bf16x8*)(As + (size_t)((r << 3) + (c8 ^ (r & 7))) * 8);
      }
#pragma unroll
      for (int tj = 0; tj < 4; ++tj) {
        bq[tj] = *(const bf16x8*)(Bs + (size_t)((c8 << 7) + rsw[tj]) * 8);
      }
#pragma unroll
      for (int ti = 0; ti < 4; ++ti)
#pragma unroll
        for (int tj = 0; tj < 4; ++tj)
          acc[ti][tj] = __builtin_amdgcn_mfma_f32_16x16x32_bf16(af[ti], bq[tj], acc[ti][tj], 0, 0, 0);
    }
    __syncthreads();   // protect LDS from next iteration's staging
  }

  // Epilogue: C/D layout col = lane&15, row = quad*4 + reg  [m89/m91 verified]
#pragma unroll
  for (int ti = 0; ti < 4; ++ti) {
    const int l = l0 + wr * 64 + ti * 16 + quad * 4;
#pragma unroll
    for (int tj = 0; tj < 4; ++tj) {
      const int d = d0 + wc * 64 + tj * 16 + col;
      float* op = out + (size_t)b * QLEN * DMODEL + (size_t)l * DMODEL + d;
#pragma unroll
      for (int r2 = 0; r2 < 4; ++r2) op[(size_t)r2 * DMODEL] = acc[ti][tj][r2];
    }
  }
}

extern "C" void kernel_launch(void* const* d_in, const int* in_sizes, int n_in,
                              void* d_out, int out_size, void* d_ws, size_t ws_size,
                              hipStream_t stream) {
  const float* x   = (const float*)d_in[0];
  const float* p   = (const float*)d_in[1];
  const int* addp  = (const int*)d_in[3];   // add_position (qlen fixed at 1024 by shapes)
  float* out = (float*)d_out;

  // FT in workspace (hipMalloc-interleaved; round-3 measured win). Fully
  // rewritten every launch before any read -> re-poisoning safe.
  const size_t FT_BYTES = (size_t)QLEN * KLEN * sizeof(__bf16);  // 4 MiB
  __bf16* ft = (d_ws && ws_size >= FT_BYTES) ? (__bf16*)d_ws : nullptr;

  prep_ft_kernel<<<dim3((QLEN * KLEN / 8) / 256), dim3(256), 0, stream>>>(ft);
  gemm_kernel<<<dim3(DMODEL / BN, QLEN / BM, BATCH), dim3(256), 0, stream>>>(out, ft, x, p, addp);
}

// Round 6
// 189.115 us; speedup vs baseline: 1.1735x; 1.1735x over previous
//
#include <hip/hip_runtime.h>
#include <hip/hip_bf16.h>
#include <cstdint>

#define QLEN   1024
#define KLEN   2048
#define DMODEL 2048
#define BATCH  4
#define FLEN   (KLEN - QLEN + 1)   // 1025

typedef __bf16 bf16x8 __attribute__((ext_vector_type(8)));
typedef float  f32x4  __attribute__((ext_vector_type(4)));

// Static device scratch — FALLBACK ONLY (round-3 measured: ws placement is
// faster than module BSS; keep both paths).
__device__ __align__(16) __bf16 g_ft[(size_t)QLEN * KLEN];           // 4 MiB
__device__ __align__(16) __bf16 g_yt[(size_t)BATCH * DMODEL * KLEN]; // 32 MiB

typedef __attribute__((address_space(1))) void gvoid;
typedef __attribute__((address_space(3))) void svoid;

__device__ __forceinline__ void async_load16(const void* g, void* lds) {
  gvoid* gp = (gvoid*)(uintptr_t)g;
  svoid* sp = (svoid*)(uint32_t)(uintptr_t)lds;   // flat LDS addr low 32 bits == LDS offset
  __builtin_amdgcn_global_load_lds(gp, sp, 16, 0, 0);
}

// ---------------- prep: y^T (blocked) + FT generation, fused ----------------
// Round-6: body identical to the measured round-3 kernel (53 us). Single
// change: 1536 blocks -> 6144 waves x exactly 6 units (round 3 had 4.5 avg ->
// 4/5-unit tail imbalance, occupancy 56%). Fused-gemm alternative refuted by
// round-5 counters (FETCH 254 MB from fp32 band amplification).
#define YT_UNITS (BATCH * (KLEN / 8) * (DMODEL / 64))  // 32768 wave-units
#define FT_UNITS ((QLEN * KLEN) / 512)                 // 4096 wave-units
#define PREP_BLOCKS 1536                               // 6144 waves * 6 = 36864 exact

__global__ __launch_bounds__(256) void prep_kernel(const float* __restrict__ x,
                                                   const float* __restrict__ p,
                                                   const int* __restrict__ addp,
                                                   __bf16* __restrict__ ftp,
                                                   __bf16* __restrict__ ytp) {
  __bf16* ft = ftp ? ftp : g_ft;
  __bf16* yt = ytp ? ytp : g_yt;
  const int lane  = threadIdx.x & 63;
  const int gw    = (blockIdx.x * 256 + threadIdx.x) >> 6;  // global wave id
  const int nw    = PREP_BLOCKS * 4;                        // 6144 waves
  const int doadd = *addp;

  for (int u = gw; u < YT_UNITS + FT_UNITS; u += nw) {
    if (u < YT_UNITS) {
      // unit -> (b, mt, 64-wide d-block); lane owns one d column, 8 m rows.
      const int b  = u >> 13;          // 8192 units per batch (256 mt * 32 db)
      const int r5 = u & 8191;
      const int mt = r5 >> 5;
      const int db = r5 & 31;
      const int d  = db * 64 + lane;
      const float* xp = x + ((size_t)b * KLEN + mt * 8) * DMODEL + d;
      float v[8];
#pragma unroll
      for (int i = 0; i < 8; ++i) v[i] = xp[(size_t)i * DMODEL];  // 256 B/instr coalesced
      if (doadd) {
        const float* pp = p + ((size_t)b * KLEN + mt * 8) * DMODEL + d;
#pragma unroll
        for (int i = 0; i < 8; ++i) v[i] += pp[(size_t)i * DMODEL];
      }
      bf16x8 o;
#pragma unroll
      for (int i = 0; i < 8; ++i) o[i] = (__bf16)v[i];
      // wave writes 64 chunks * 16 B = contiguous 1 KB
      *(bf16x8*)(yt + ((size_t)b * (KLEN / 8) * DMODEL + (size_t)mt * DMODEL + d) * 8) = o;
    } else {
      // FT[l,m] = cos(2*pi*((l*(m-l)) % 1025)/1025)/sqrt(1025*2048) in band.
      const int uu = (u - YT_UNITS) * 64 + lane;   // [0, QLEN*KLEN/8)
      const int l  = uu >> 8;                      // KLEN/8 = 256 chunks per row
      const int m0 = (uu & 255) * 8;
      const int j0 = m0 - l;
      bf16x8 o = {};
      if (j0 + 7 >= 0 && j0 < FLEN) {
        const float w     = 6.283185307179586f / (float)FLEN;
        const float scale = 1.0f / sqrtf((float)FLEN * (float)KLEN);
#pragma unroll
        for (int i = 0; i < 8; ++i) {
          const int j = j0 + i;
          float vv = 0.0f;
          if (j >= 0 && j < FLEN) {
            const int rr = (l * j) % FLEN;         // exact: l*j < 2^20, magic-mul mod
            vv = cosf((float)rr * w) * scale;
          }
          o[i] = (__bf16)vv;
        }
      }
      *(bf16x8*)(ft + (size_t)uu * 8) = o;
    }
  }
}

// ---------------- GEMM: out[b][l][d] = sum_m FT[l][m] * y[m][d] ----------------
#define BM 128
#define BN 128
#define BK 64

__global__ __launch_bounds__(256) void gemm_kernel(float* __restrict__ out,
                                                   const __bf16* __restrict__ ftq,
                                                   const __bf16* __restrict__ ytq) {
  // grid: flat 512 blocks; XCD chunk-swizzle (T1/m204): dispatch round-robins
  // consecutive hw ids across the 8 XCDs, so hw id i -> logical (i%8)*64+i/8.
  // XCD x then owns logical blocks [64x,64x+64) = 4 bm x 16 bn of one batch:
  // same-bm blocks share the identical 295 KB ft K-slab and overlapping y
  // band-slabs -> staging served from per-XCD L2 (35 TB/s) instead of L3.
  __shared__ __align__(16) __bf16 As[BM * BK];   // [l'][k'] chunk-swizzled, 16 KB
  __shared__ __align__(16) __bf16 Bs[BN * BK];   // chunk-major: chunk (c8, d') at idx c8*128+d', 16 KB
  const int flat = blockIdx.x;                    // 0..511
  const int swz  = (flat & 7) * 64 + (flat >> 3); // bijective (512 = 8*64)
  const int bn = swz & 15, bm = (swz >> 4) & 7, b = swz >> 7;
  const int l0 = bm * BM, d0 = bn * BN;
  const int tid  = threadIdx.x;
  const int lane = tid & 63;
  const int wave = tid >> 6;
  const int wr = wave >> 1, wc = wave & 1;
  const int col = lane & 15, quad = lane >> 4;

  f32x4 acc[4][4] = {};

  // band: FT[l,m] nonzero only for l <= m <= l+1024 -> K-tiles [l0/64, (l0+1151)/64]
  const int t0 = l0 >> 6;
  const int t1 = (l0 + BM - 1 + FLEN - 1) >> 6;   // inclusive; 18 tiles
  const __bf16* ftp = ftq ? ftq : g_ft;
  const __bf16* ytp = (ytq ? ytq : g_yt) + (size_t)b * DMODEL * KLEN;  // blocked [mt][d][8]

  for (int t = t0; t <= t1; ++t) {
    const int k0 = t * BK;
    // Stage A (FT): 128 rows x 64 k row-major, XOR swizzle on the GLOBAL side
    // (LDS linear; global_load_lds writes lane i at base + i*16).
#pragma unroll
    for (int s = 0; s < 4; ++s) {
      const int cb  = wave * 256 + s * 64;
      const int lc  = cb + lane;
      const int row = lc >> 3;
      const int gc8 = (lc & 7) ^ (row & 7);
      async_load16(ftp + (size_t)(l0 + row) * KLEN + k0 + gc8 * 8, As + cb * 8);
    }
    // Stage B (blocked y^T): chunk-major LDS, chunk (c, dd) <- yt[t*8+c][d0+dd].
    // Sweep lanes hit consecutive dd for fixed c -> contiguous 1 KB source reads.
    // Frag-read addr16 = c8*128 + r: residues r%8 cover all 8 bank groups -> no
    // swizzle needed (same distribution as the measured-0-conflict A path).
#pragma unroll
    for (int s = 0; s < 4; ++s) {
      const int idx = wave * 256 + s * 64 + lane;   // 0..1023
      const int c   = idx >> 7;                     // k-chunk 0..7
      const int dd  = idx & 127;
      async_load16(ytp + ((size_t)(t * 8 + c) * DMODEL + (d0 + dd)) * 8, Bs + (size_t)idx * 8);
    }
    __syncthreads();   // drains vmcnt -> staged data visible

#pragma unroll
    for (int kk = 0; kk < 2; ++kk) {
      bf16x8 af[4], bq[4];
      const int c8 = kk * 4 + quad;
#pragma unroll
      for (int ti = 0; ti < 4; ++ti) {
        const int r = wr * 64 + ti * 16 + col;            // A row (l), frag m = lane&15
        af[ti] = *(const bf16x8*)(As + (size_t)((r << 3) + (c8 ^ (r & 7))) * 8);
      }
#pragma unroll
      for (int tj = 0; tj < 4; ++tj) {
        const int r = wc * 64 + tj * 16 + col;            // B row (d), frag n = lane&15
        bq[tj] = *(const bf16x8*)(Bs + (size_t)((c8 << 7) + r) * 8);
      }
#pragma unroll
      for (int ti = 0; ti < 4; ++ti)
#pragma unroll
        for (int tj = 0; tj < 4; ++tj)
          acc[ti][tj] = __builtin_amdgcn_mfma_f32_16x16x32_bf16(af[ti], bq[tj], acc[ti][tj], 0, 0, 0);
    }
    __syncthreads();   // protect LDS from next iteration's staging
  }

  // Epilogue: C/D layout col = lane&15, row = quad*4 + reg  [m89/m91 verified]
#pragma unroll
  for (int ti = 0; ti < 4; ++ti) {
    const int l = l0 + wr * 64 + ti * 16 + quad * 4;
#pragma unroll
    for (int tj = 0; tj < 4; ++tj) {
      const int d = d0 + wc * 64 + tj * 16 + col;
      float* op = out + (size_t)b * QLEN * DMODEL + (size_t)l * DMODEL + d;
#pragma unroll
      for (int r2 = 0; r2 < 4; ++r2) op[(size_t)r2 * DMODEL] = acc[ti][tj][r2];
    }
  }
}

extern "C" void kernel_launch(void* const* d_in, const int* in_sizes, int n_in,
                              void* d_out, int out_size, void* d_ws, size_t ws_size,
                              hipStream_t stream) {
  const float* x   = (const float*)d_in[0];
  const float* p   = (const float*)d_in[1];
  const int* addp  = (const int*)d_in[3];   // add_position (qlen fixed at 1024 by shapes)
  float* out = (float*)d_out;

  // Workspace placement (round-3 measured win): ft/yt in properly interleaved
  // hipMalloc memory. Both arrays fully rewritten every launch before any read,
  // so ws re-poisoning is safe.
  const size_t FT_BYTES = (size_t)QLEN * KLEN * sizeof(__bf16);            // 4 MiB
  const size_t YT_BYTES = (size_t)BATCH * DMODEL * KLEN * sizeof(__bf16);  // 32 MiB
  __bf16* ft = nullptr;
  __bf16* yt = nullptr;
  char* ws = (char*)d_ws;
  if (ws && ws_size >= FT_BYTES + YT_BYTES) {
    ft = (__bf16*)ws;
    yt = (__bf16*)(ws + FT_BYTES);
  } else if (ws && ws_size >= YT_BYTES) {
    yt = (__bf16*)ws;           // prioritize the hot 32 MiB array
  }

  prep_kernel<<<dim3(PREP_BLOCKS), dim3(256), 0, stream>>>(x, p, addp, ft, yt);
  gemm_kernel<<<dim3(512), dim3(256), 0, stream>>>(out, ft, yt);
}